// Round 3
// baseline (5286.169 us; speedup 1.0000x reference)
//
#include <hip/hip_runtime.h>
#include <cstdint>

// Block_32401233281211: SAM-style windowed-attention transformer block.
// I/O dtype: FLOAT32 (per reference setup_inputs). Internal GEMMs: bf16 MFMA.
// B=8, H=W=64, C=768, heads=12, hd=64, FF=3072, WS=14 -> pad to 70x70,
// 200 windows x 196 tokens = 39200 window-token rows.
// Chunked pipeline: 4 chunks of 50 windows (9800 rows) for LN1/QKV/attn/proj,
// 4 chunks of 8192 tokens for LN2/fc1/fc2.  Total ws use: 79,540,224 B.

typedef unsigned short u16;
typedef __attribute__((ext_vector_type(8))) short short8;   // 8 x bf16 (4 VGPRs)
typedef __attribute__((ext_vector_type(4))) float f32x4;

__device__ __forceinline__ u16 f2b(float f) {
    union { float f; unsigned int i; } x; x.f = f;
    unsigned int u = x.i;
    return (u16)((u + 0x7fffu + ((u >> 16) & 1u)) >> 16);   // RNE
}
__device__ __forceinline__ float b2f(u16 u) {
    union { unsigned int i; float f; } x; x.i = ((unsigned int)u) << 16; return x.f;
}

// ---------------------------------------------------------------- transpose
// in: R x C f32 (row-major) -> out: C x R bf16 (row-major). R,C mult of 32.
__global__ __launch_bounds__(256) void transpose_k(
    const float* __restrict__ in, u16* __restrict__ out, int R, int C)
{
    __shared__ float tile[32][33];
    int bpc = C >> 5;
    int r0 = (blockIdx.x / bpc) << 5;
    int c0 = (blockIdx.x % bpc) << 5;
    int lx = threadIdx.x & 31, ly = threadIdx.x >> 5;   // ly 0..7
#pragma unroll
    for (int s = 0; s < 32; s += 8)
        tile[ly + s][lx] = in[(size_t)(r0 + ly + s) * C + c0 + lx];
    __syncthreads();
#pragma unroll
    for (int s = 0; s < 32; s += 8)
        out[(size_t)(c0 + ly + s) * R + r0 + lx] = f2b(tile[lx][ly + s]);
}

// ---------------------------------------------------------------- layernorm
// f32 in -> bf16 out.
// windowed=1: row (row_base+blockIdx.x) is a padded-window-token row; pad
// rows write zeros. in = full x tensor (8,64,64,768). out row = blockIdx.x.
// windowed=0: plain rows; in already offset; out row = blockIdx.x.
__global__ __launch_bounds__(256) void ln_kernel(
    const float* __restrict__ in, const float* __restrict__ g,
    const float* __restrict__ beta, u16* __restrict__ out, int windowed,
    int row_base)
{
    __shared__ float sbuf[4];
    int tid = threadIdx.x;
    size_t orow = (size_t)blockIdx.x * 768;
    size_t irow;
    if (windowed) {
        int r = row_base + blockIdx.x;
        int win = r / 196, t = r % 196;
        int p = t / 14, q = t % 14;
        int b = win / 25, wt = win % 25;
        int i = (wt / 5) * 14 + p, j = (wt % 5) * 14 + q;
        if (i >= 64 || j >= 64) {                // pad token -> zeros
            out[orow + tid] = 0; out[orow + tid + 256] = 0; out[orow + tid + 512] = 0;
            return;
        }
        irow = (((size_t)b * 64 + i) * 64 + j) * 768;
    } else {
        irow = (size_t)blockIdx.x * 768;
    }
    float v0 = in[irow + tid];
    float v1 = in[irow + tid + 256];
    float v2 = in[irow + tid + 512];
    float s = v0 + v1 + v2;
#pragma unroll
    for (int off = 32; off; off >>= 1) s += __shfl_xor(s, off, 64);
    if ((tid & 63) == 0) sbuf[tid >> 6] = s;
    __syncthreads();
    float mean = (sbuf[0] + sbuf[1] + sbuf[2] + sbuf[3]) * (1.f / 768.f);
    __syncthreads();
    float d0 = v0 - mean, d1 = v1 - mean, d2 = v2 - mean;
    float sq = d0 * d0 + d1 * d1 + d2 * d2;
#pragma unroll
    for (int off = 32; off; off >>= 1) sq += __shfl_xor(sq, off, 64);
    if ((tid & 63) == 0) sbuf[tid >> 6] = sq;
    __syncthreads();
    float var = (sbuf[0] + sbuf[1] + sbuf[2] + sbuf[3]) * (1.f / 768.f);
    float rs = rsqrtf(var + 1e-6f);
    out[orow + tid]       = f2b(d0 * rs * g[tid]       + beta[tid]);
    out[orow + tid + 256] = f2b(d1 * rs * g[tid + 256] + beta[tid + 256]);
    out[orow + tid + 512] = f2b(d2 * rs * g[tid + 512] + beta[tid + 512]);
}

// ---------------------------------------------------------------- GEMM
// C(MxN) = A(MxK) @ Bt(NxK)^T + bias, bf16 in / f32 acc, MFMA 16x16x32.
// 128x128 tile, BK=32, 4 waves in 2x2, each wave 64x64 via 4x4 frags.
// Staging: 2 threads per tile-row, each thread 16 elems (2 x uint4 = 32 B)
// -> full 128x32 bf16 tile (8 KB) covered by 256 threads.
// EPI: 0 = store bf16 (Cout u16*); 1 = proj scatter-unpartition + residual
//        (resid/Cout f32, global window row = row_base+row);
//      2 = exact GELU store bf16; 3 = residual-add into f32 Cout rows.
#define BM 128
#define BN 128
#define BK 32

template <int EPI>
__global__ __launch_bounds__(256) void gemm_bt(
    const u16* __restrict__ A, const u16* __restrict__ Bt,
    const float* __restrict__ bias, void* __restrict__ CoutV,
    const float* __restrict__ resid, int M, int N, int K, int row_base)
{
    __shared__ __align__(16) u16 As[BM * BK];
    __shared__ __align__(16) u16 Bs[BN * BK];
    const int tid = threadIdx.x;
    const int lane = tid & 63, wave = tid >> 6;
    const int wr = wave >> 1, wc = wave & 1;
    const int quad = lane >> 4, l16 = lane & 15;
    const int ntile = N / BN;
    const int m0 = (blockIdx.x / ntile) * BM;
    const int n0 = (blockIdx.x % ntile) * BN;
    const int srow = tid >> 1;              // 2 threads per staged row
    const int scol = (tid & 1) << 4;        // 16-elem (32 B) half-row

    f32x4 acc[4][4] = {};

    const u16* Aptr = A + (size_t)(m0 + srow) * K + scol;
    const u16* Bptr = Bt + (size_t)(n0 + srow) * K + scol;
    const bool avalid = (m0 + srow) < M;

    for (int k0 = 0; k0 < K; k0 += BK) {
        uint4 av0 = make_uint4(0u,0u,0u,0u), av1 = make_uint4(0u,0u,0u,0u);
        if (avalid) {
            av0 = *(const uint4*)(Aptr + k0);
            av1 = *(const uint4*)(Aptr + k0 + 8);
        }
        uint4 bv0 = *(const uint4*)(Bptr + k0);
        uint4 bv1 = *(const uint4*)(Bptr + k0 + 8);
        __syncthreads();                     // previous tile fully consumed
        *(uint4*)(As + srow * BK + scol)     = av0;
        *(uint4*)(As + srow * BK + scol + 8) = av1;
        *(uint4*)(Bs + srow * BK + scol)     = bv0;
        *(uint4*)(Bs + srow * BK + scol + 8) = bv1;
        __syncthreads();
        short8 af[4], bfr[4];
#pragma unroll
        for (int i = 0; i < 4; i++)
            af[i] = *(const short8*)(As + (wr * 64 + i * 16 + l16) * BK + quad * 8);
#pragma unroll
        for (int i = 0; i < 4; i++)
            bfr[i] = *(const short8*)(Bs + (wc * 64 + i * 16 + l16) * BK + quad * 8);
#pragma unroll
        for (int mi = 0; mi < 4; mi++)
#pragma unroll
            for (int ni = 0; ni < 4; ni++)
                acc[mi][ni] = __builtin_amdgcn_mfma_f32_16x16x32_bf16(
                    af[mi], bfr[ni], acc[mi][ni], 0, 0, 0);
    }

    // epilogue: D row = quad*4+r (+16mi+64wr), col = l16 (+16ni+64wc)
#pragma unroll
    for (int mi = 0; mi < 4; mi++) {
#pragma unroll
        for (int ni = 0; ni < 4; ni++) {
            const int gn = n0 + wc * 64 + ni * 16 + l16;
            const float bv = bias[gn];
#pragma unroll
            for (int r = 0; r < 4; r++) {
                const int row = m0 + wr * 64 + mi * 16 + quad * 4 + r;
                if (row >= M) continue;
                float v = acc[mi][ni][r] + bv;
                if (EPI == 0) {
                    ((u16*)CoutV)[(size_t)row * N + gn] = f2b(v);
                } else if (EPI == 1) {
                    int grow = row_base + row;
                    int win = grow / 196, t = grow % 196;
                    int p = t / 14, q = t % 14;
                    int b = win / 25, wt = win % 25;
                    int i = (wt / 5) * 14 + p, j = (wt % 5) * 14 + q;
                    if (i < 64 && j < 64) {
                        size_t idx = (((size_t)b * 64 + i) * 64 + j) * 768 + gn;
                        ((float*)CoutV)[idx] = resid[idx] + v;   // x2 = x + attn
                    }
                } else if (EPI == 2) {
                    float gl = 0.5f * v * (1.0f + erff(v * 0.70710678118654752f));
                    ((u16*)CoutV)[(size_t)row * N + gn] = f2b(gl);
                } else {
                    size_t idx = (size_t)(row_base + row) * 768 + gn;
                    ((float*)CoutV)[idx] = resid[idx] + v;       // out = x2+mlp
                }
            }
        }
    }
}

// ---------------------------------------------------------------- attention
// One block per (local window, head). 196 query threads (of 256), online
// softmax. K/V staged as f32 in LDS in two 98-key chunks (7 kp-rows each).
// qkv = this chunk's rows only, bf16 [nw*196][2304]=[..][3][12][64].
__global__ __launch_bounds__(256) void attn_kernel(
    const u16* __restrict__ qkv,
    const float* __restrict__ relh, const float* __restrict__ relw, // [27][64]
    u16* __restrict__ out)                // [nw*196][768]
{
    __shared__ float ks[98 * 64];
    __shared__ float vs[98 * 64];
    __shared__ float rh_t[27 * 64];
    __shared__ float rw_t[27 * 64];

    const int bid = blockIdx.x;
    const int win = bid / 12, head = bid % 12;     // local window
    const int tid = threadIdx.x;
    const bool active = tid < 196;
    const int tok = active ? tid : 0;

    for (int e = tid; e < 27 * 64; e += 256) {
        rh_t[e] = relh[e];
        rw_t[e] = relw[e];
    }

    float qv[64];
    const size_t qbase = ((size_t)(win * 196 + tok)) * 2304 + head * 64;
#pragma unroll
    for (int d = 0; d < 64; d++) qv[d] = b2f(qkv[qbase + d]);

    const int p = tok / 14, qq = tok % 14;

    float m = -1e30f, l = 0.f;
    float o[64];
#pragma unroll
    for (int d = 0; d < 64; d++) o[d] = 0.f;

#pragma unroll 1
    for (int c = 0; c < 2; c++) {
        __syncthreads();   // prior chunk consumed (also orders rel staging)
        for (int e = tid; e < 98 * 64; e += 256) {
            int kk = e >> 6, d = e & 63;
            size_t kb = ((size_t)(win * 196 + 98 * c + kk)) * 2304 + head * 64 + d;
            ks[e] = b2f(qkv[kb + 768]);
            vs[e] = b2f(qkv[kb + 1536]);
        }
        __syncthreads();
#pragma unroll 1
        for (int kp7 = 0; kp7 < 7; kp7++) {
            const int kp = 7 * c + kp7;
            float bh = 0.f;
            {
                const float4* R = (const float4*)(rh_t + (p - kp + 13) * 64);
#pragma unroll
                for (int i = 0; i < 16; i++) {
                    float4 t = R[i];
                    bh += qv[4*i]*t.x + qv[4*i+1]*t.y + qv[4*i+2]*t.z + qv[4*i+3]*t.w;
                }
            }
#pragma unroll 1
            for (int kq = 0; kq < 14; kq++) {
                float bw = 0.f;
                {
                    const float4* R = (const float4*)(rw_t + (qq - kq + 13) * 64);
#pragma unroll
                    for (int i = 0; i < 16; i++) {
                        float4 t = R[i];
                        bw += qv[4*i]*t.x + qv[4*i+1]*t.y + qv[4*i+2]*t.z + qv[4*i+3]*t.w;
                    }
                }
                float s = 0.f;
                {
                    const float4* Kr = (const float4*)(ks + (kp7 * 14 + kq) * 64);
#pragma unroll
                    for (int i = 0; i < 16; i++) {
                        float4 t = Kr[i];
                        s += qv[4*i]*t.x + qv[4*i+1]*t.y + qv[4*i+2]*t.z + qv[4*i+3]*t.w;
                    }
                }
                s = s * 0.125f + bh + bw;
                float mn = fmaxf(m, s);
                float alpha = __expf(m - mn);
                float pe = __expf(s - mn);
                l = l * alpha + pe;
                {
                    const float4* Vr = (const float4*)(vs + (kp7 * 14 + kq) * 64);
#pragma unroll
                    for (int i = 0; i < 16; i++) {
                        float4 t = Vr[i];
                        o[4*i]   = o[4*i]   * alpha + pe * t.x;
                        o[4*i+1] = o[4*i+1] * alpha + pe * t.y;
                        o[4*i+2] = o[4*i+2] * alpha + pe * t.z;
                        o[4*i+3] = o[4*i+3] * alpha + pe * t.w;
                    }
                }
                m = mn;
            }
        }
    }

    if (active) {
        float inv = 1.f / l;
        size_t ob = ((size_t)(win * 196 + tok)) * 768 + head * 64;
#pragma unroll
        for (int d = 0; d < 64; d++) out[ob + d] = f2b(o[d] * inv);
    }
}

// ---------------------------------------------------------------- launch
extern "C" void kernel_launch(void* const* d_in, const int* in_sizes, int n_in,
                              void* d_out, int out_size, void* d_ws, size_t ws_size,
                              hipStream_t stream)
{
    const float* x      = (const float*)d_in[0];
    const float* g1     = (const float*)d_in[1];
    const float* beta1  = (const float*)d_in[2];
    const float* w_qkv  = (const float*)d_in[3];
    const float* b_qkv  = (const float*)d_in[4];
    const float* w_proj = (const float*)d_in[5];
    const float* b_proj = (const float*)d_in[6];
    const float* rph    = (const float*)d_in[7];
    const float* rpw    = (const float*)d_in[8];
    const float* g2     = (const float*)d_in[9];
    const float* beta2  = (const float*)d_in[10];
    const float* w_fc1  = (const float*)d_in[11];
    const float* b_fc1  = (const float*)d_in[12];
    const float* w_fc2  = (const float*)d_in[13];
    const float* b_fc2  = (const float*)d_in[14];
    float* out = (float*)d_out;

    // ws layout (79,540,224 B total), all internal buffers bf16:
    //   wt:   transposed weights (NxK)                     14,155,776 B @ 0
    //   buf1: h_win/attn_out chunk (9800x768) | h2 chunk   15,052,800 B
    //   buf2: qkv chunk (9800x2304) | mlp mid (8192x3072)  50,331,648 B
    if (ws_size < 79540224) return;   // diagnostic: leaves d_out untouched
    char* ws = (char*)d_ws;
    u16* wt0 = (u16*)ws;                               // qkv^T  2304x768
    u16* wt1 = wt0 + 2304 * 768;                       // proj^T  768x768
    u16* wt2 = wt1 + 768 * 768;                        // fc1^T  3072x768
    u16* wt3 = wt2 + 3072 * 768;                       // fc2^T   768x3072
    u16* buf1 = (u16*)(ws + 14155776);
    u16* buf2 = (u16*)(ws + 14155776 + 15052800);

    dim3 blk(256);

    transpose_k<<<(768/32)*(2304/32), blk, 0, stream>>>(w_qkv,  wt0, 768, 2304);
    transpose_k<<<(768/32)*(768/32),  blk, 0, stream>>>(w_proj, wt1, 768, 768);
    transpose_k<<<(768/32)*(3072/32), blk, 0, stream>>>(w_fc1,  wt2, 768, 3072);
    transpose_k<<<(3072/32)*(768/32), blk, 0, stream>>>(w_fc2,  wt3, 3072, 768);

    // ---- attention phase: 4 chunks of 50 windows (9800 rows) ----
    for (int c = 0; c < 4; c++) {
        const int rb = c * 9800;
        // LN1 fused with window partition (pad rows zeroed) -> buf1 (bf16)
        ln_kernel<<<9800, blk, 0, stream>>>(x, g1, beta1, buf1, 1, rb);
        // QKV: (9800x768) @ (768x2304) + b -> buf2 (bf16)
        gemm_bt<0><<<dim3(77 * (2304/128)), blk, 0, stream>>>(
            buf1, wt0, b_qkv, buf2, nullptr, 9800, 2304, 768, 0);
        // windowed attention -> buf1 (aliases h_win; h_win already consumed)
        attn_kernel<<<50 * 12, blk, 0, stream>>>(buf2, rph, rpw, buf1);
        // proj + window-unpartition + residual(x, f32) -> d_out holds x2
        gemm_bt<1><<<dim3(77 * (768/128)), blk, 0, stream>>>(
            buf1, wt1, b_proj, out, x, 9800, 768, 768, rb);
    }

    // ---- MLP phase: 4 chunks of 8192 tokens ----
    for (int c = 0; c < 4; c++) {
        const int rb = c * 8192;
        // LN2 over x2 chunk (f32) -> buf1 (bf16)
        ln_kernel<<<8192, blk, 0, stream>>>(
            out + (size_t)rb * 768, g2, beta2, buf1, 0, 0);
        // fc1 + exact GELU: (8192x768) @ (768x3072) -> buf2 (bf16)
        gemm_bt<2><<<dim3((8192/128) * (3072/128)), blk, 0, stream>>>(
            buf1, wt2, b_fc1, buf2, nullptr, 8192, 3072, 768, 0);
        // fc2 + residual into f32 d_out rows [rb, rb+8192)
        gemm_bt<3><<<dim3((8192/128) * (768/128)), blk, 0, stream>>>(
            buf2, wt3, b_fc2, out, out, 8192, 768, 3072, rb);
    }
}

// Round 4
// 2034.585 us; speedup vs baseline: 2.5982x; 2.5982x over previous
//
#include <hip/hip_runtime.h>
#include <cstdint>

// Block_32401233281211: SAM-style windowed-attention transformer block.
// I/O dtype: FLOAT32 (per reference). Internal GEMMs + attention: bf16 MFMA.
// B=8, H=W=64, C=768, heads=12, hd=64, FF=3072, WS=14 -> pad to 70x70,
// 200 windows x 196 tokens = 39200 window-token rows.
// R4: MFMA flash attention (was scalar-VALU, 4x1005us, 2.6e8 bank conflicts).

typedef unsigned short u16;
typedef __attribute__((ext_vector_type(8))) short short8;   // 8 x bf16 (4 VGPRs)
typedef __attribute__((ext_vector_type(4))) float f32x4;

__device__ __forceinline__ u16 f2b(float f) {
    union { float f; unsigned int i; } x; x.f = f;
    unsigned int u = x.i;
    return (u16)((u + 0x7fffu + ((u >> 16) & 1u)) >> 16);   // RNE
}
__device__ __forceinline__ float b2f(u16 u) {
    union { unsigned int i; float f; } x; x.i = ((unsigned int)u) << 16; return x.f;
}

// ---------------------------------------------------------------- transpose
// in: R x C f32 (row-major) -> out: C x R bf16 (row-major). R,C mult of 32.
__global__ __launch_bounds__(256) void transpose_k(
    const float* __restrict__ in, u16* __restrict__ out, int R, int C)
{
    __shared__ float tile[32][33];
    int bpc = C >> 5;
    int r0 = (blockIdx.x / bpc) << 5;
    int c0 = (blockIdx.x % bpc) << 5;
    int lx = threadIdx.x & 31, ly = threadIdx.x >> 5;   // ly 0..7
#pragma unroll
    for (int s = 0; s < 32; s += 8)
        tile[ly + s][lx] = in[(size_t)(r0 + ly + s) * C + c0 + lx];
    __syncthreads();
#pragma unroll
    for (int s = 0; s < 32; s += 8)
        out[(size_t)(c0 + ly + s) * R + r0 + lx] = f2b(tile[lx][ly + s]);
}

// ---------------------------------------------------------------- layernorm
__global__ __launch_bounds__(256) void ln_kernel(
    const float* __restrict__ in, const float* __restrict__ g,
    const float* __restrict__ beta, u16* __restrict__ out, int windowed,
    int row_base)
{
    __shared__ float sbuf[4];
    int tid = threadIdx.x;
    size_t orow = (size_t)blockIdx.x * 768;
    size_t irow;
    if (windowed) {
        int r = row_base + blockIdx.x;
        int win = r / 196, t = r % 196;
        int p = t / 14, q = t % 14;
        int b = win / 25, wt = win % 25;
        int i = (wt / 5) * 14 + p, j = (wt % 5) * 14 + q;
        if (i >= 64 || j >= 64) {                // pad token -> zeros
            out[orow + tid] = 0; out[orow + tid + 256] = 0; out[orow + tid + 512] = 0;
            return;
        }
        irow = (((size_t)b * 64 + i) * 64 + j) * 768;
    } else {
        irow = (size_t)blockIdx.x * 768;
    }
    float v0 = in[irow + tid];
    float v1 = in[irow + tid + 256];
    float v2 = in[irow + tid + 512];
    float s = v0 + v1 + v2;
#pragma unroll
    for (int off = 32; off; off >>= 1) s += __shfl_xor(s, off, 64);
    if ((tid & 63) == 0) sbuf[tid >> 6] = s;
    __syncthreads();
    float mean = (sbuf[0] + sbuf[1] + sbuf[2] + sbuf[3]) * (1.f / 768.f);
    __syncthreads();
    float d0 = v0 - mean, d1 = v1 - mean, d2 = v2 - mean;
    float sq = d0 * d0 + d1 * d1 + d2 * d2;
#pragma unroll
    for (int off = 32; off; off >>= 1) sq += __shfl_xor(sq, off, 64);
    if ((tid & 63) == 0) sbuf[tid >> 6] = sq;
    __syncthreads();
    float var = (sbuf[0] + sbuf[1] + sbuf[2] + sbuf[3]) * (1.f / 768.f);
    float rs = rsqrtf(var + 1e-6f);
    out[orow + tid]       = f2b(d0 * rs * g[tid]       + beta[tid]);
    out[orow + tid + 256] = f2b(d1 * rs * g[tid + 256] + beta[tid + 256]);
    out[orow + tid + 512] = f2b(d2 * rs * g[tid + 512] + beta[tid + 512]);
}

// ---------------------------------------------------------------- GEMM
// (unchanged from passing R3 kernel)
#define BM 128
#define BN 128
#define BK 32

template <int EPI>
__global__ __launch_bounds__(256) void gemm_bt(
    const u16* __restrict__ A, const u16* __restrict__ Bt,
    const float* __restrict__ bias, void* __restrict__ CoutV,
    const float* __restrict__ resid, int M, int N, int K, int row_base)
{
    __shared__ __align__(16) u16 As[BM * BK];
    __shared__ __align__(16) u16 Bs[BN * BK];
    const int tid = threadIdx.x;
    const int lane = tid & 63, wave = tid >> 6;
    const int wr = wave >> 1, wc = wave & 1;
    const int quad = lane >> 4, l16 = lane & 15;
    const int ntile = N / BN;
    const int m0 = (blockIdx.x / ntile) * BM;
    const int n0 = (blockIdx.x % ntile) * BN;
    const int srow = tid >> 1;
    const int scol = (tid & 1) << 4;

    f32x4 acc[4][4] = {};

    const u16* Aptr = A + (size_t)(m0 + srow) * K + scol;
    const u16* Bptr = Bt + (size_t)(n0 + srow) * K + scol;
    const bool avalid = (m0 + srow) < M;

    for (int k0 = 0; k0 < K; k0 += BK) {
        uint4 av0 = make_uint4(0u,0u,0u,0u), av1 = make_uint4(0u,0u,0u,0u);
        if (avalid) {
            av0 = *(const uint4*)(Aptr + k0);
            av1 = *(const uint4*)(Aptr + k0 + 8);
        }
        uint4 bv0 = *(const uint4*)(Bptr + k0);
        uint4 bv1 = *(const uint4*)(Bptr + k0 + 8);
        __syncthreads();
        *(uint4*)(As + srow * BK + scol)     = av0;
        *(uint4*)(As + srow * BK + scol + 8) = av1;
        *(uint4*)(Bs + srow * BK + scol)     = bv0;
        *(uint4*)(Bs + srow * BK + scol + 8) = bv1;
        __syncthreads();
        short8 af[4], bfr[4];
#pragma unroll
        for (int i = 0; i < 4; i++)
            af[i] = *(const short8*)(As + (wr * 64 + i * 16 + l16) * BK + quad * 8);
#pragma unroll
        for (int i = 0; i < 4; i++)
            bfr[i] = *(const short8*)(Bs + (wc * 64 + i * 16 + l16) * BK + quad * 8);
#pragma unroll
        for (int mi = 0; mi < 4; mi++)
#pragma unroll
            for (int ni = 0; ni < 4; ni++)
                acc[mi][ni] = __builtin_amdgcn_mfma_f32_16x16x32_bf16(
                    af[mi], bfr[ni], acc[mi][ni], 0, 0, 0);
    }

#pragma unroll
    for (int mi = 0; mi < 4; mi++) {
#pragma unroll
        for (int ni = 0; ni < 4; ni++) {
            const int gn = n0 + wc * 64 + ni * 16 + l16;
            const float bv = bias[gn];
#pragma unroll
            for (int r = 0; r < 4; r++) {
                const int row = m0 + wr * 64 + mi * 16 + quad * 4 + r;
                if (row >= M) continue;
                float v = acc[mi][ni][r] + bv;
                if (EPI == 0) {
                    ((u16*)CoutV)[(size_t)row * N + gn] = f2b(v);
                } else if (EPI == 1) {
                    int grow = row_base + row;
                    int win = grow / 196, t = grow % 196;
                    int p = t / 14, q = t % 14;
                    int b = win / 25, wt = win % 25;
                    int i = (wt / 5) * 14 + p, j = (wt % 5) * 14 + q;
                    if (i < 64 && j < 64) {
                        size_t idx = (((size_t)b * 64 + i) * 64 + j) * 768 + gn;
                        ((float*)CoutV)[idx] = resid[idx] + v;
                    }
                } else if (EPI == 2) {
                    float gl = 0.5f * v * (1.0f + erff(v * 0.70710678118654752f));
                    ((u16*)CoutV)[(size_t)row * N + gn] = f2b(gl);
                } else {
                    size_t idx = (size_t)(row_base + row) * 768 + gn;
                    ((float*)CoutV)[idx] = resid[idx] + v;
                }
            }
        }
    }
}

// ---------------------------------------------------------------- attention
// MFMA flash attention. Block = (local window, head), 4 waves.
// Wave w owns query rows [64w, 64w+64) of M=256 (196 real, pad clamped).
// Keys: 7 chunks of 32 (196 real + 28 masked). S = Q*K^T via mfma (K staged
// [key][hd], same B-pattern as gemm_bt). P -> A-layout via per-wave LDS buf.
// PV via mfma with V staged transposed [hd][key].
// Rel-pos bias: pre-pass mfma GEMM Q @ [Rh;Rw]^T -> rel_all[256][56] bf16;
// inner loop gathers 2 scalars per score.
__global__ __launch_bounds__(256) void attn_mfma(
    const u16* __restrict__ qkv,          // [nw*196][2304] = [..][3][12][64]
    const float* __restrict__ relh, const float* __restrict__ relw, // [27][64]
    u16* __restrict__ out)                // [nw*196][768]
{
    __shared__ u16 rel_all[256 * 56];     // 28,672 B  (cols 0-26 bh, 27-53 bw)
    __shared__ __align__(16) u16 kvbuf[4096];  // 8 KB: Kb[64][64] | Kc[32][64]+Vt[64][32]
    __shared__ __align__(16) u16 pbuf[4][64 * 32];  // 16 KB

    u16* Kb = kvbuf;            // bias pre-pass: [64][64]
    u16* Kc = kvbuf;            // K chunk: [32][64]
    u16* Vt = kvbuf + 2048;     // V^T chunk: [64][32]

    const int win = blockIdx.x / 12, head = blockIdx.x % 12;
    const int tid = threadIdx.x, lane = tid & 63, wave = tid >> 6;
    const int quad = lane >> 4, l16 = lane & 15;
    const size_t base = (size_t)win * 196 * 2304 + (size_t)head * 64;

    // ---- Q fragments (A-operand: m=l16, k=quad*8+j), rows clamped to 195
    short8 qf[4][2];
#pragma unroll
    for (int mi = 0; mi < 4; mi++) {
        int tok = wave * 64 + mi * 16 + l16;
        int rt = tok < 196 ? tok : 195;
        const u16* qp = qkv + base + (size_t)rt * 2304 + quad * 8;
        qf[mi][0] = *(const short8*)(qp);
        qf[mi][1] = *(const short8*)(qp + 32);
    }

    // ---- bias pre-pass: stage [Rh(27); Rw(27); 0(10)] as Kb[64][64] bf16
    for (int e = tid; e < 64 * 64; e += 256) {
        int rrow = e >> 6, c = e & 63;
        float v = 0.f;
        if (rrow < 27)      v = relh[rrow * 64 + c];
        else if (rrow < 54) v = relw[(rrow - 27) * 64 + c];
        Kb[e] = f2b(v);
    }
    __syncthreads();
    // rel_all[row][col] = dot(q_row, bias_row_col)  (q UNSCALED per reference)
#pragma unroll
    for (int cb = 0; cb < 2; cb++) {
#pragma unroll
        for (int nt = 0; nt < 2; nt++) {
            const u16* kp_ = Kb + (cb * 32 + nt * 16 + l16) * 64 + quad * 8;
            short8 b0 = *(const short8*)(kp_);
            short8 b1 = *(const short8*)(kp_ + 32);
            int col = cb * 32 + nt * 16 + l16;
#pragma unroll
            for (int mi = 0; mi < 4; mi++) {
                f32x4 c = {};
                c = __builtin_amdgcn_mfma_f32_16x16x32_bf16(qf[mi][0], b0, c, 0, 0, 0);
                c = __builtin_amdgcn_mfma_f32_16x16x32_bf16(qf[mi][1], b1, c, 0, 0, 0);
                if (col < 56) {
#pragma unroll
                    for (int r = 0; r < 4; r++) {
                        int row = wave * 64 + mi * 16 + quad * 4 + r;
                        rel_all[row * 56 + col] = f2b(c[r]);
                    }
                }
            }
        }
    }
    // rel_all: each wave writes/reads only its own rows -> no barrier needed.
    // Kb -> Kc/Vt alias protected by the barrier at top of chunk loop.

    f32x4 acc[4][4] = {};
    float ml[4][4], ll[4][4];
#pragma unroll
    for (int mi = 0; mi < 4; mi++)
#pragma unroll
        for (int r = 0; r < 4; r++) { ml[mi][r] = -1e30f; ll[mi][r] = 0.f; }

#pragma unroll 1
    for (int c = 0; c < 7; c++) {
        const int kbase = c * 32;
        __syncthreads();               // prior Kc/Vt (or Kb) fully consumed
        {
            int row = tid >> 3;        // 0..31  key-in-chunk
            int cg = (tid & 7) * 8;    // hd col group
            int key = kbase + row;
            uint4 kv_ = make_uint4(0u, 0u, 0u, 0u), vv_ = make_uint4(0u, 0u, 0u, 0u);
            if (key < 196) {
                kv_ = *(const uint4*)(qkv + base + 768  + (size_t)key * 2304 + cg);
                vv_ = *(const uint4*)(qkv + base + 1536 + (size_t)key * 2304 + cg);
            }
            *(uint4*)(Kc + row * 64 + cg) = kv_;
            union { uint4 u; u16 h[8]; } vu; vu.u = vv_;
#pragma unroll
            for (int i = 0; i < 8; i++) Vt[(cg + i) * 32 + row] = vu.h[i];
        }
        __syncthreads();

        // K fragments for both n-tiles (B-operand: n=l16, k=quad*8+j)
        short8 kf0[2], kf1[2];
#pragma unroll
        for (int nt = 0; nt < 2; nt++) {
            const u16* kp_ = Kc + (nt * 16 + l16) * 64 + quad * 8;
            kf0[nt] = *(const short8*)(kp_);
            kf1[nt] = *(const short8*)(kp_ + 32);
        }

#pragma unroll
        for (int mi = 0; mi < 4; mi++) {
            // S = Q K^T  (two k-steps of 32)
            f32x4 s[2];
#pragma unroll
            for (int nt = 0; nt < 2; nt++) {
                f32x4 t = {};
                t = __builtin_amdgcn_mfma_f32_16x16x32_bf16(qf[mi][0], kf0[nt], t, 0, 0, 0);
                t = __builtin_amdgcn_mfma_f32_16x16x32_bf16(qf[mi][1], kf1[nt], t, 0, 0, 0);
                s[nt] = t;
            }
            // bias + scale + mask  (C/D: row=quad*4+r, col=l16)
#pragma unroll
            for (int r = 0; r < 4; r++) {
                int tok = wave * 64 + mi * 16 + quad * 4 + r;
                int rt = tok < 196 ? tok : 195;
                int p = rt / 14, qq = rt % 14;
                const u16* ra = rel_all + tok * 56;
#pragma unroll
                for (int nt = 0; nt < 2; nt++) {
                    int key = kbase + nt * 16 + l16;
                    bool valid = key < 196;
                    int kk = valid ? key : 0;
                    int kp = kk / 14, kq = kk % 14;
                    float bh = b2f(ra[p - kp + 13]);
                    float bw = b2f(ra[27 + qq - kq + 13]);
                    float sv = s[nt][r] * 0.125f + bh + bw;
                    s[nt][r] = valid ? sv : -1e30f;
                }
            }
            // online softmax per row (reduce over 16-lane quad group)
#pragma unroll
            for (int r = 0; r < 4; r++) {
                float mx = fmaxf(s[0][r], s[1][r]);
#pragma unroll
                for (int off = 8; off; off >>= 1) mx = fmaxf(mx, __shfl_xor(mx, off, 16));
                float mn = fmaxf(ml[mi][r], mx);
                float alpha = __expf(ml[mi][r] - mn);
                ml[mi][r] = mn;
                float p0 = __expf(s[0][r] - mn);
                float p1 = __expf(s[1][r] - mn);
                s[0][r] = p0; s[1][r] = p1;
                float ps = p0 + p1;
#pragma unroll
                for (int off = 8; off; off >>= 1) ps += __shfl_xor(ps, off, 16);
                ll[mi][r] = ll[mi][r] * alpha + ps;
#pragma unroll
                for (int ni = 0; ni < 4; ni++) acc[mi][ni][r] *= alpha;
            }
            // P (C/D layout) -> pbuf [q-row][key] bf16
#pragma unroll
            for (int nt = 0; nt < 2; nt++)
#pragma unroll
                for (int r = 0; r < 4; r++)
                    pbuf[wave][(mi * 16 + quad * 4 + r) * 32 + nt * 16 + l16] = f2b(s[nt][r]);
        }

        // PV: A = P from pbuf (m=l16, k'=quad*8+j over 32 keys), B = Vt[n=hd][k=key]
        short8 vf[4], pf[4];
#pragma unroll
        for (int ni = 0; ni < 4; ni++)
            vf[ni] = *(const short8*)(Vt + (ni * 16 + l16) * 32 + quad * 8);
#pragma unroll
        for (int mi = 0; mi < 4; mi++)
            pf[mi] = *(const short8*)(pbuf[wave] + (mi * 16 + l16) * 32 + quad * 8);
#pragma unroll
        for (int mi = 0; mi < 4; mi++)
#pragma unroll
            for (int ni = 0; ni < 4; ni++)
                acc[mi][ni] = __builtin_amdgcn_mfma_f32_16x16x32_bf16(
                    pf[mi], vf[ni], acc[mi][ni], 0, 0, 0);
    }

    // epilogue: O / l  -> out (bf16), rows < 196 only
#pragma unroll
    for (int mi = 0; mi < 4; mi++) {
#pragma unroll
        for (int r = 0; r < 4; r++) {
            int tok = wave * 64 + mi * 16 + quad * 4 + r;
            if (tok < 196) {
                float inv = 1.f / ll[mi][r];
                size_t ob = (size_t)(win * 196 + tok) * 768 + head * 64;
#pragma unroll
                for (int ni = 0; ni < 4; ni++)
                    out[ob + ni * 16 + l16] = f2b(acc[mi][ni][r] * inv);
            }
        }
    }
}

// ---------------------------------------------------------------- launch
extern "C" void kernel_launch(void* const* d_in, const int* in_sizes, int n_in,
                              void* d_out, int out_size, void* d_ws, size_t ws_size,
                              hipStream_t stream)
{
    const float* x      = (const float*)d_in[0];
    const float* g1     = (const float*)d_in[1];
    const float* beta1  = (const float*)d_in[2];
    const float* w_qkv  = (const float*)d_in[3];
    const float* b_qkv  = (const float*)d_in[4];
    const float* w_proj = (const float*)d_in[5];
    const float* b_proj = (const float*)d_in[6];
    const float* rph    = (const float*)d_in[7];
    const float* rpw    = (const float*)d_in[8];
    const float* g2     = (const float*)d_in[9];
    const float* beta2  = (const float*)d_in[10];
    const float* w_fc1  = (const float*)d_in[11];
    const float* b_fc1  = (const float*)d_in[12];
    const float* w_fc2  = (const float*)d_in[13];
    const float* b_fc2  = (const float*)d_in[14];
    float* out = (float*)d_out;

    // ws layout (79,540,224 B total), all internal buffers bf16:
    //   wt:   transposed weights (NxK)                     14,155,776 B @ 0
    //   buf1: h_win/attn_out chunk (9800x768) | h2 chunk   15,052,800 B
    //   buf2: qkv chunk (9800x2304) | mlp mid (8192x3072)  50,331,648 B
    if (ws_size < 79540224) return;   // diagnostic: leaves d_out untouched
    char* ws = (char*)d_ws;
    u16* wt0 = (u16*)ws;                               // qkv^T  2304x768
    u16* wt1 = wt0 + 2304 * 768;                       // proj^T  768x768
    u16* wt2 = wt1 + 768 * 768;                        // fc1^T  3072x768
    u16* wt3 = wt2 + 3072 * 768;                       // fc2^T   768x3072
    u16* buf1 = (u16*)(ws + 14155776);
    u16* buf2 = (u16*)(ws + 14155776 + 15052800);

    dim3 blk(256);

    transpose_k<<<(768/32)*(2304/32), blk, 0, stream>>>(w_qkv,  wt0, 768, 2304);
    transpose_k<<<(768/32)*(768/32),  blk, 0, stream>>>(w_proj, wt1, 768, 768);
    transpose_k<<<(768/32)*(3072/32), blk, 0, stream>>>(w_fc1,  wt2, 768, 3072);
    transpose_k<<<(3072/32)*(768/32), blk, 0, stream>>>(w_fc2,  wt3, 3072, 768);

    // ---- attention phase: 4 chunks of 50 windows (9800 rows) ----
    for (int c = 0; c < 4; c++) {
        const int rb = c * 9800;
        ln_kernel<<<9800, blk, 0, stream>>>(x, g1, beta1, buf1, 1, rb);
        gemm_bt<0><<<dim3(77 * (2304/128)), blk, 0, stream>>>(
            buf1, wt0, b_qkv, buf2, nullptr, 9800, 2304, 768, 0);
        attn_mfma<<<50 * 12, blk, 0, stream>>>(buf2, rph, rpw, buf1);
        gemm_bt<1><<<dim3(77 * (768/128)), blk, 0, stream>>>(
            buf1, wt1, b_proj, out, x, 9800, 768, 768, rb);
    }

    // ---- MLP phase: 4 chunks of 8192 tokens ----
    for (int c = 0; c < 4; c++) {
        const int rb = c * 8192;
        ln_kernel<<<8192, blk, 0, stream>>>(
            out + (size_t)rb * 768, g2, beta2, buf1, 0, 0);
        gemm_bt<2><<<dim3((8192/128) * (3072/128)), blk, 0, stream>>>(
            buf1, wt2, b_fc1, buf2, nullptr, 8192, 3072, 768, 0);
        gemm_bt<3><<<dim3((8192/128) * (768/128)), blk, 0, stream>>>(
            buf2, wt3, b_fc2, out, out, 8192, 768, 3072, rb);
    }
}

// Round 5
// 1617.798 us; speedup vs baseline: 3.2675x; 1.2576x over previous
//
#include <hip/hip_runtime.h>
#include <cstdint>

// Block_32401233281211: SAM-style windowed-attention transformer block.
// I/O dtype: FLOAT32. Internal GEMMs + attention: bf16 MFMA.
// B=8, H=W=64, C=768, heads=12, hd=64, FF=3072, WS=14 -> pad to 70x70,
// 200 windows x 196 tokens = 39200 window-token rows.
// R5: attention v3 - bias+mask fused into MFMA via extended-K one-hot trick,
// 64-key chunks, padded LDS strides, host-adaptive ws chunking.

typedef unsigned short u16;
typedef __attribute__((ext_vector_type(8))) short short8;   // 8 x bf16
typedef __attribute__((ext_vector_type(4))) float f32x4;

__device__ __forceinline__ u16 f2b(float f) {
    union { float f; unsigned int i; } x; x.f = f;
    unsigned int u = x.i;
    return (u16)((u + 0x7fffu + ((u >> 16) & 1u)) >> 16);   // RNE
}
__device__ __forceinline__ float b2f(u16 u) {
    union { unsigned int i; float f; } x; x.i = ((unsigned int)u) << 16; return x.f;
}

// ---------------------------------------------------------------- transpose
__global__ __launch_bounds__(256) void transpose_k(
    const float* __restrict__ in, u16* __restrict__ out, int R, int C)
{
    __shared__ float tile[32][33];
    int bpc = C >> 5;
    int r0 = (blockIdx.x / bpc) << 5;
    int c0 = (blockIdx.x % bpc) << 5;
    int lx = threadIdx.x & 31, ly = threadIdx.x >> 5;
#pragma unroll
    for (int s = 0; s < 32; s += 8)
        tile[ly + s][lx] = in[(size_t)(r0 + ly + s) * C + c0 + lx];
    __syncthreads();
#pragma unroll
    for (int s = 0; s < 32; s += 8)
        out[(size_t)(c0 + ly + s) * R + r0 + lx] = f2b(tile[lx][ly + s]);
}

// ---------------------------------------------------------------- layernorm
__global__ __launch_bounds__(256) void ln_kernel(
    const float* __restrict__ in, const float* __restrict__ g,
    const float* __restrict__ beta, u16* __restrict__ out, int windowed,
    int row_base)
{
    __shared__ float sbuf[4];
    int tid = threadIdx.x;
    size_t orow = (size_t)blockIdx.x * 768;
    size_t irow;
    if (windowed) {
        int r = row_base + blockIdx.x;
        int win = r / 196, t = r % 196;
        int p = t / 14, q = t % 14;
        int b = win / 25, wt = win % 25;
        int i = (wt / 5) * 14 + p, j = (wt % 5) * 14 + q;
        if (i >= 64 || j >= 64) {
            out[orow + tid] = 0; out[orow + tid + 256] = 0; out[orow + tid + 512] = 0;
            return;
        }
        irow = (((size_t)b * 64 + i) * 64 + j) * 768;
    } else {
        irow = (size_t)blockIdx.x * 768;
    }
    float v0 = in[irow + tid];
    float v1 = in[irow + tid + 256];
    float v2 = in[irow + tid + 512];
    float s = v0 + v1 + v2;
#pragma unroll
    for (int off = 32; off; off >>= 1) s += __shfl_xor(s, off, 64);
    if ((tid & 63) == 0) sbuf[tid >> 6] = s;
    __syncthreads();
    float mean = (sbuf[0] + sbuf[1] + sbuf[2] + sbuf[3]) * (1.f / 768.f);
    __syncthreads();
    float d0 = v0 - mean, d1 = v1 - mean, d2 = v2 - mean;
    float sq = d0 * d0 + d1 * d1 + d2 * d2;
#pragma unroll
    for (int off = 32; off; off >>= 1) sq += __shfl_xor(sq, off, 64);
    if ((tid & 63) == 0) sbuf[tid >> 6] = sq;
    __syncthreads();
    float var = (sbuf[0] + sbuf[1] + sbuf[2] + sbuf[3]) * (1.f / 768.f);
    float rs = rsqrtf(var + 1e-6f);
    out[orow + tid]       = f2b(d0 * rs * g[tid]       + beta[tid]);
    out[orow + tid + 256] = f2b(d1 * rs * g[tid + 256] + beta[tid + 256]);
    out[orow + tid + 512] = f2b(d2 * rs * g[tid + 512] + beta[tid + 512]);
}

// ---------------------------------------------------------------- GEMM
// (unchanged, verified in R3/R4)
#define BM 128
#define BN 128
#define BK 32

template <int EPI>
__global__ __launch_bounds__(256) void gemm_bt(
    const u16* __restrict__ A, const u16* __restrict__ Bt,
    const float* __restrict__ bias, void* __restrict__ CoutV,
    const float* __restrict__ resid, int M, int N, int K, int row_base)
{
    __shared__ __align__(16) u16 As[BM * BK];
    __shared__ __align__(16) u16 Bs[BN * BK];
    const int tid = threadIdx.x;
    const int lane = tid & 63, wave = tid >> 6;
    const int wr = wave >> 1, wc = wave & 1;
    const int quad = lane >> 4, l16 = lane & 15;
    const int ntile = N / BN;
    const int m0 = (blockIdx.x / ntile) * BM;
    const int n0 = (blockIdx.x % ntile) * BN;
    const int srow = tid >> 1;
    const int scol = (tid & 1) << 4;

    f32x4 acc[4][4] = {};

    const u16* Aptr = A + (size_t)(m0 + srow) * K + scol;
    const u16* Bptr = Bt + (size_t)(n0 + srow) * K + scol;
    const bool avalid = (m0 + srow) < M;

    for (int k0 = 0; k0 < K; k0 += BK) {
        uint4 av0 = make_uint4(0u,0u,0u,0u), av1 = make_uint4(0u,0u,0u,0u);
        if (avalid) {
            av0 = *(const uint4*)(Aptr + k0);
            av1 = *(const uint4*)(Aptr + k0 + 8);
        }
        uint4 bv0 = *(const uint4*)(Bptr + k0);
        uint4 bv1 = *(const uint4*)(Bptr + k0 + 8);
        __syncthreads();
        *(uint4*)(As + srow * BK + scol)     = av0;
        *(uint4*)(As + srow * BK + scol + 8) = av1;
        *(uint4*)(Bs + srow * BK + scol)     = bv0;
        *(uint4*)(Bs + srow * BK + scol + 8) = bv1;
        __syncthreads();
        short8 af[4], bfr[4];
#pragma unroll
        for (int i = 0; i < 4; i++)
            af[i] = *(const short8*)(As + (wr * 64 + i * 16 + l16) * BK + quad * 8);
#pragma unroll
        for (int i = 0; i < 4; i++)
            bfr[i] = *(const short8*)(Bs + (wc * 64 + i * 16 + l16) * BK + quad * 8);
#pragma unroll
        for (int mi = 0; mi < 4; mi++)
#pragma unroll
            for (int ni = 0; ni < 4; ni++)
                acc[mi][ni] = __builtin_amdgcn_mfma_f32_16x16x32_bf16(
                    af[mi], bfr[ni], acc[mi][ni], 0, 0, 0);
    }

#pragma unroll
    for (int mi = 0; mi < 4; mi++) {
#pragma unroll
        for (int ni = 0; ni < 4; ni++) {
            const int gn = n0 + wc * 64 + ni * 16 + l16;
            const float bv = bias[gn];
#pragma unroll
            for (int r = 0; r < 4; r++) {
                const int row = m0 + wr * 64 + mi * 16 + quad * 4 + r;
                if (row >= M) continue;
                float v = acc[mi][ni][r] + bv;
                if (EPI == 0) {
                    ((u16*)CoutV)[(size_t)row * N + gn] = f2b(v);
                } else if (EPI == 1) {
                    int grow = row_base + row;
                    int win = grow / 196, t = grow % 196;
                    int p = t / 14, q = t % 14;
                    int b = win / 25, wt = win % 25;
                    int i = (wt / 5) * 14 + p, j = (wt % 5) * 14 + q;
                    if (i < 64 && j < 64) {
                        size_t idx = (((size_t)b * 64 + i) * 64 + j) * 768 + gn;
                        ((float*)CoutV)[idx] = resid[idx] + v;
                    }
                } else if (EPI == 2) {
                    float gl = 0.5f * v * (1.0f + erff(v * 0.70710678118654752f));
                    ((u16*)CoutV)[(size_t)row * N + gn] = f2b(gl);
                } else {
                    size_t idx = (size_t)(row_base + row) * 768 + gn;
                    ((float*)CoutV)[idx] = resid[idx] + v;
                }
            }
        }
    }
}

// ---------------------------------------------------------------- attention v3
// Block = (local window, head), 4 waves x 64 query rows. 4 chunks of 64 keys.
// Extended-K MFMA: S_raw = q.k + A3.B3 where A3[row] = [bh'(14), bw'(14), 0,0,0, -1e30]
// (bh'[t] = 8*q.Rh[p+13-t] so selecting t=kp gives the reference bias*8),
// B3[key] = one-hot [d(t=kp), d(t-14=kq), ..., d(invalid)] built in registers.
// S = S_raw * 0.125. Online softmax per 64-key chunk; PV in two 32-key halves
// via wave-private pbuf (LDS pipe is in-order per wave).
#define AT_W 72   // Kc/Vt row stride (64+8): 144 B rows, 16B-aligned, 2-way banks
#define PB_W 40   // pbuf row stride (32+8):  80 B rows, 16B-aligned, 2-way banks

__global__ __launch_bounds__(256) void attn_mfma(
    const u16* __restrict__ qkv,          // [nw*196][2304] = [..][3][12][64]
    const float* __restrict__ relh, const float* __restrict__ relw, // [27][64]
    u16* __restrict__ out)                // [nw*196][768]
{
    __shared__ __align__(16) u16 rel_ext[256 * 32];      // 16384 B
    __shared__ __align__(16) u16 Kc[64 * AT_W];          //  9216 B (aliased w/ Kb)
    __shared__ __align__(16) u16 Vt[64 * AT_W];          //  9216 B
    __shared__ __align__(16) u16 pbuf[4][64 * PB_W];     // 20480 B   total 55296

    const int win = blockIdx.x / 12, head = blockIdx.x % 12;
    const int tid = threadIdx.x, lane = tid & 63, wave = tid >> 6;
    const int quad = lane >> 4, l16 = lane & 15;
    const size_t base = (size_t)win * 196 * 2304 + (size_t)head * 64;

    // ---- Q fragments (A-operand: m=l16, k=quad*8+j), pad rows clamp to 195
    short8 qf[4][2];
#pragma unroll
    for (int mi = 0; mi < 4; mi++) {
        int tok = wave * 64 + mi * 16 + l16;
        int rt = tok < 196 ? tok : 195;
        const u16* qp = qkv + base + (size_t)rt * 2304 + quad * 8;
        qf[mi][0] = *(const short8*)(qp);
        qf[mi][1] = *(const short8*)(qp + 32);
    }

    // ---- stage Kb = [8*Rh(27); 8*Rw(27); 0(10)] into Kc region; init rel_ext
    for (int e = tid; e < 64 * 64; e += 256) {
        int rr = e >> 6, cc = e & 63;
        float v = 0.f;
        if (rr < 27)      v = 8.f * relh[rr * 64 + cc];
        else if (rr < 54) v = 8.f * relw[(rr - 27) * 64 + cc];
        Kc[rr * AT_W + cc] = f2b(v);
    }
    {   // zero rel_ext row, set mask col 31 = -1e30 (one row per thread)
        u16* rp = rel_ext + tid * 32;
        uint4 z = make_uint4(0u, 0u, 0u, 0u);
        *(uint4*)(rp) = z; *(uint4*)(rp + 8) = z;
        *(uint4*)(rp + 16) = z; *(uint4*)(rp + 24) = z;
        rp[31] = f2b(-1e30f);
    }
    __syncthreads();

    // ---- bias pre-pass: d[row][i] = q_row . Kb_i, scatter-permute into rel_ext
#pragma unroll
    for (int cb = 0; cb < 2; cb++) {
#pragma unroll
        for (int nt = 0; nt < 2; nt++) {
            const u16* kp_ = Kc + (cb * 32 + nt * 16 + l16) * AT_W + quad * 8;
            short8 b0 = *(const short8*)(kp_);
            short8 b1 = *(const short8*)(kp_ + 32);
            int i = cb * 32 + nt * 16 + l16;
#pragma unroll
            for (int mi = 0; mi < 4; mi++) {
                f32x4 c = {};
                c = __builtin_amdgcn_mfma_f32_16x16x32_bf16(qf[mi][0], b0, c, 0, 0, 0);
                c = __builtin_amdgcn_mfma_f32_16x16x32_bf16(qf[mi][1], b1, c, 0, 0, 0);
#pragma unroll
                for (int r = 0; r < 4; r++) {
                    int row = wave * 64 + mi * 16 + quad * 4 + r;
                    int rowB = row < 196 ? row : 195;
                    int p = rowB / 14, qq = rowB % 14;
                    if (i < 27) {
                        int t = p + 13 - i;
                        if (t >= 0 && t < 14) rel_ext[row * 32 + t] = f2b(c[r]);
                    } else if (i < 54) {
                        int t = qq + 13 - (i - 27);
                        if (t >= 0 && t < 14) rel_ext[row * 32 + 14 + t] = f2b(c[r]);
                    }
                }
            }
        }
    }
    // A3 fragment (wave-private rows; DS in-order makes scatter->read safe)
    short8 qe[4];
#pragma unroll
    for (int mi = 0; mi < 4; mi++)
        qe[mi] = *(const short8*)(rel_ext + (wave * 64 + mi * 16 + l16) * 32 + quad * 8);

    f32x4 acc[4][4] = {};
    float ml_[4][4], ll_[4][4];
#pragma unroll
    for (int mi = 0; mi < 4; mi++)
#pragma unroll
        for (int r = 0; r < 4; r++) { ml_[mi][r] = -1e30f; ll_[mi][r] = 0.f; }

#pragma unroll 1
    for (int c = 0; c < 4; c++) {
        const int kbase = c * 64;
        __syncthreads();               // Kb/prepass reads done; prior chunk consumed
        {   // stage K chunk [64][64] and V^T [64][64]
            int key = tid >> 2;                 // 0..63
            int cg  = (tid & 3) << 4;           // 0,16,32,48
            int gk = kbase + key;
            uint4 k0 = make_uint4(0u,0u,0u,0u), k1 = k0, v0 = k0, v1 = k0;
            if (gk < 196) {
                const u16* kp_ = qkv + base + 768  + (size_t)gk * 2304 + cg;
                const u16* vp_ = qkv + base + 1536 + (size_t)gk * 2304 + cg;
                k0 = *(const uint4*)(kp_); k1 = *(const uint4*)(kp_ + 8);
                v0 = *(const uint4*)(vp_); v1 = *(const uint4*)(vp_ + 8);
            }
            *(uint4*)(Kc + key * AT_W + cg)     = k0;
            *(uint4*)(Kc + key * AT_W + cg + 8) = k1;
            union { uint4 u; u16 h[8]; } a, b; a.u = v0; b.u = v1;
#pragma unroll
            for (int i = 0; i < 8; i++) Vt[(cg + i) * AT_W + key] = a.h[i];
#pragma unroll
            for (int i = 0; i < 8; i++) Vt[(cg + 8 + i) * AT_W + key] = b.h[i];
        }
        __syncthreads();

        // one-hot B3 fragments (registers)
        short8 bo[4];
        {
            const u16 one = 0x3F80;
#pragma unroll
            for (int nt = 0; nt < 4; nt++) {
                int key = kbase + nt * 16 + l16;
                int inval = key >= 196;
                int kp = key / 14, kq = key - kp * 14;
                union { short8 s; u16 h[8]; } u;
#pragma unroll
                for (int j = 0; j < 8; j++) {
                    int t = quad * 8 + j;
                    u16 v = 0;
                    if (!inval && t == kp) v = one;
                    if (!inval && t >= 14 && (t - 14) == kq) v = one;
                    if (inval && t == 31) v = one;
                    u.h[j] = v;
                }
                bo[nt] = u.s;
            }
        }

        f32x4 s23[4][2];
#pragma unroll
        for (int mi = 0; mi < 4; mi++) {
            f32x4 s[4];
#pragma unroll
            for (int nt = 0; nt < 4; nt++) {
                const u16* kp_ = Kc + (nt * 16 + l16) * AT_W + quad * 8;
                short8 kf0 = *(const short8*)(kp_);
                short8 kf1 = *(const short8*)(kp_ + 32);
                f32x4 t = {};
                t = __builtin_amdgcn_mfma_f32_16x16x32_bf16(qf[mi][0], kf0, t, 0, 0, 0);
                t = __builtin_amdgcn_mfma_f32_16x16x32_bf16(qf[mi][1], kf1, t, 0, 0, 0);
                t = __builtin_amdgcn_mfma_f32_16x16x32_bf16(qe[mi],    bo[nt], t, 0, 0, 0);
                s[nt] = t * 0.125f;
            }
            // online softmax (row = quad*4+r, reduce over l16 within quad group)
#pragma unroll
            for (int r = 0; r < 4; r++) {
                float mx = fmaxf(fmaxf(s[0][r], s[1][r]), fmaxf(s[2][r], s[3][r]));
#pragma unroll
                for (int off = 8; off; off >>= 1) mx = fmaxf(mx, __shfl_xor(mx, off, 16));
                float mo = ml_[mi][r];
                float mn = fmaxf(mo, mx);
                float alpha = __expf(mo - mn);
                ml_[mi][r] = mn;
                float p0 = __expf(s[0][r] - mn), p1 = __expf(s[1][r] - mn);
                float p2 = __expf(s[2][r] - mn), p3 = __expf(s[3][r] - mn);
                float ps = (p0 + p1) + (p2 + p3);
#pragma unroll
                for (int off = 8; off; off >>= 1) ps += __shfl_xor(ps, off, 16);
                ll_[mi][r] = ll_[mi][r] * alpha + ps;
#pragma unroll
                for (int ni = 0; ni < 4; ni++) acc[mi][ni][r] *= alpha;
                s[0][r] = p0; s[1][r] = p1; s[2][r] = p2; s[3][r] = p3;
            }
            // store P half0 (keys 0..31), keep half1 in regs
#pragma unroll
            for (int nt = 0; nt < 2; nt++)
#pragma unroll
                for (int r = 0; r < 4; r++)
                    pbuf[wave][(mi * 16 + quad * 4 + r) * PB_W + nt * 16 + l16] = f2b(s[nt][r]);
            s23[mi][0] = s[2]; s23[mi][1] = s[3];
        }

        // PV half 0
#pragma unroll
        for (int mi = 0; mi < 4; mi++) {
            short8 pf = *(const short8*)(pbuf[wave] + (mi * 16 + l16) * PB_W + quad * 8);
#pragma unroll
            for (int ni = 0; ni < 4; ni++) {
                short8 vfn = *(const short8*)(Vt + (ni * 16 + l16) * AT_W + quad * 8);
                acc[mi][ni] = __builtin_amdgcn_mfma_f32_16x16x32_bf16(pf, vfn, acc[mi][ni], 0, 0, 0);
            }
        }
        // store P half1 (overwrites half0; wave-private, DS pipe in-order)
#pragma unroll
        for (int mi = 0; mi < 4; mi++)
#pragma unroll
            for (int h = 0; h < 2; h++)
#pragma unroll
                for (int r = 0; r < 4; r++)
                    pbuf[wave][(mi * 16 + quad * 4 + r) * PB_W + h * 16 + l16] = f2b(s23[mi][h][r]);
        // PV half 1
#pragma unroll
        for (int mi = 0; mi < 4; mi++) {
            short8 pf = *(const short8*)(pbuf[wave] + (mi * 16 + l16) * PB_W + quad * 8);
#pragma unroll
            for (int ni = 0; ni < 4; ni++) {
                short8 vfn = *(const short8*)(Vt + (ni * 16 + l16) * AT_W + 32 + quad * 8);
                acc[mi][ni] = __builtin_amdgcn_mfma_f32_16x16x32_bf16(pf, vfn, acc[mi][ni], 0, 0, 0);
            }
        }
    }

    // epilogue: O / l  -> out (bf16), rows < 196 only
#pragma unroll
    for (int mi = 0; mi < 4; mi++)
#pragma unroll
        for (int r = 0; r < 4; r++) {
            int tok = wave * 64 + mi * 16 + quad * 4 + r;
            if (tok < 196) {
                float inv = 1.f / ll_[mi][r];
                size_t ob = (size_t)(win * 196 + tok) * 768 + head * 64;
#pragma unroll
                for (int ni = 0; ni < 4; ni++)
                    out[ob + ni * 16 + l16] = f2b(acc[mi][ni][r] * inv);
            }
        }
}

// ---------------------------------------------------------------- launch
extern "C" void kernel_launch(void* const* d_in, const int* in_sizes, int n_in,
                              void* d_out, int out_size, void* d_ws, size_t ws_size,
                              hipStream_t stream)
{
    const float* x      = (const float*)d_in[0];
    const float* g1     = (const float*)d_in[1];
    const float* beta1  = (const float*)d_in[2];
    const float* w_qkv  = (const float*)d_in[3];
    const float* b_qkv  = (const float*)d_in[4];
    const float* w_proj = (const float*)d_in[5];
    const float* b_proj = (const float*)d_in[6];
    const float* rph    = (const float*)d_in[7];
    const float* rpw    = (const float*)d_in[8];
    const float* g2     = (const float*)d_in[9];
    const float* beta2  = (const float*)d_in[10];
    const float* w_fc1  = (const float*)d_in[11];
    const float* b_fc1  = (const float*)d_in[12];
    const float* w_fc2  = (const float*)d_in[13];
    const float* b_fc2  = (const float*)d_in[14];
    float* out = (float*)d_out;

    // Adaptive ws layout: wt(14.16MB) + buf1 + buf2; chunk counts (nc windows-
    // phase, mc token-phase) picked largest-first to fit ws_size.
    const size_t WT = 14155776;
    size_t b1 = 0, b2 = 0;
    int nc = 0, mc = 0;
    auto fits = [&](int a, int m) -> bool {
        size_t rows = (size_t)(200 / a) * 196, toks = (size_t)32768 / m;
        size_t bb1 = rows * 768 * 2 >= toks * 768 * 2 ? rows * 768 * 2 : toks * 768 * 2;
        size_t bb2 = rows * 2304 * 2 >= toks * 3072 * 2 ? rows * 2304 * 2 : toks * 3072 * 2;
        if (WT + bb1 + bb2 <= ws_size) { b1 = bb1; b2 = bb2; nc = a; mc = m; return true; }
        return false;
    };
    if (!fits(1, 1) && !fits(1, 2) && !fits(2, 2) && !fits(2, 4) && !fits(4, 4))
        return;   // diagnostic: leaves d_out untouched

    char* ws = (char*)d_ws;
    u16* wt0 = (u16*)ws;                               // qkv^T  2304x768
    u16* wt1 = wt0 + 2304 * 768;                       // proj^T  768x768
    u16* wt2 = wt1 + 768 * 768;                        // fc1^T  3072x768
    u16* wt3 = wt2 + 3072 * 768;                       // fc2^T   768x3072
    u16* buf1 = (u16*)(ws + WT);
    u16* buf2 = (u16*)(ws + WT + b1);

    dim3 blk(256);

    transpose_k<<<(768/32)*(2304/32), blk, 0, stream>>>(w_qkv,  wt0, 768, 2304);
    transpose_k<<<(768/32)*(768/32),  blk, 0, stream>>>(w_proj, wt1, 768, 768);
    transpose_k<<<(768/32)*(3072/32), blk, 0, stream>>>(w_fc1,  wt2, 768, 3072);
    transpose_k<<<(3072/32)*(768/32), blk, 0, stream>>>(w_fc2,  wt3, 3072, 768);

    // ---- attention phase: nc chunks of (200/nc) windows ----
    {
        const int nw = 200 / nc, rows = nw * 196;
        const int mt = (rows + 127) / 128;
        for (int c = 0; c < nc; c++) {
            const int rb = c * rows;
            ln_kernel<<<rows, blk, 0, stream>>>(x, g1, beta1, buf1, 1, rb);
            gemm_bt<0><<<dim3(mt * (2304/128)), blk, 0, stream>>>(
                buf1, wt0, b_qkv, buf2, nullptr, rows, 2304, 768, 0);
            attn_mfma<<<nw * 12, blk, 0, stream>>>(buf2, rph, rpw, buf1);
            gemm_bt<1><<<dim3(mt * (768/128)), blk, 0, stream>>>(
                buf1, wt1, b_proj, out, x, rows, 768, 768, rb);
        }
    }

    // ---- MLP phase: mc chunks of (32768/mc) tokens ----
    {
        const int tk = 32768 / mc;
        const int mt2 = tk / 128;
        for (int c = 0; c < mc; c++) {
            const int rb = c * tk;
            ln_kernel<<<tk, blk, 0, stream>>>(
                out + (size_t)rb * 768, g2, beta2, buf1, 0, 0);
            gemm_bt<2><<<dim3(mt2 * (3072/128)), blk, 0, stream>>>(
                buf1, wt2, b_fc1, buf2, nullptr, tk, 3072, 768, 0);
            gemm_bt<3><<<dim3(mt2 * (768/128)), blk, 0, stream>>>(
                buf2, wt3, b_fc2, out, out, tk, 768, 3072, rb);
        }
    }
}

// Round 6
// 1614.849 us; speedup vs baseline: 3.2735x; 1.0018x over previous
//
#include <hip/hip_runtime.h>
#include <cstdint>

// Block_32401233281211: SAM-style windowed-attention transformer block.
// I/O dtype: FLOAT32. Internal GEMMs + attention: bf16 MFMA.
// B=8, H=W=64, C=768, heads=12, hd=64, FF=3072, WS=14 -> pad to 70x70,
// 200 windows x 196 tokens = 39200 window-token rows.
// R6: GEMM staging via global_load_lds width=16 (m97 technique). Attention
// unchanged from R5 (latency-capped at VGPR=172 -> 2 blocks/CU).

typedef unsigned short u16;
typedef __attribute__((ext_vector_type(8))) short short8;   // 8 x bf16
typedef __attribute__((ext_vector_type(4))) float f32x4;

__device__ __forceinline__ u16 f2b(float f) {
    union { float f; unsigned int i; } x; x.f = f;
    unsigned int u = x.i;
    return (u16)((u + 0x7fffu + ((u >> 16) & 1u)) >> 16);   // RNE
}
__device__ __forceinline__ float b2f(u16 u) {
    union { unsigned int i; float f; } x; x.i = ((unsigned int)u) << 16; return x.f;
}

// async global->LDS, 16 B per lane. LDS dest = wave-uniform base + lane*16.
__device__ __forceinline__ void gload16(const u16* g, u16* l) {
    __builtin_amdgcn_global_load_lds(
        (const __attribute__((address_space(1))) unsigned int*)g,
        (__attribute__((address_space(3))) unsigned int*)l, 16, 0, 0);
}

// ---------------------------------------------------------------- transpose
__global__ __launch_bounds__(256) void transpose_k(
    const float* __restrict__ in, u16* __restrict__ out, int R, int C)
{
    __shared__ float tile[32][33];
    int bpc = C >> 5;
    int r0 = (blockIdx.x / bpc) << 5;
    int c0 = (blockIdx.x % bpc) << 5;
    int lx = threadIdx.x & 31, ly = threadIdx.x >> 5;
#pragma unroll
    for (int s = 0; s < 32; s += 8)
        tile[ly + s][lx] = in[(size_t)(r0 + ly + s) * C + c0 + lx];
    __syncthreads();
#pragma unroll
    for (int s = 0; s < 32; s += 8)
        out[(size_t)(c0 + ly + s) * R + r0 + lx] = f2b(tile[lx][ly + s]);
}

// ---------------------------------------------------------------- layernorm
__global__ __launch_bounds__(256) void ln_kernel(
    const float* __restrict__ in, const float* __restrict__ g,
    const float* __restrict__ beta, u16* __restrict__ out, int windowed,
    int row_base)
{
    __shared__ float sbuf[4];
    int tid = threadIdx.x;
    size_t orow = (size_t)blockIdx.x * 768;
    size_t irow;
    if (windowed) {
        int r = row_base + blockIdx.x;
        int win = r / 196, t = r % 196;
        int p = t / 14, q = t % 14;
        int b = win / 25, wt = win % 25;
        int i = (wt / 5) * 14 + p, j = (wt % 5) * 14 + q;
        if (i >= 64 || j >= 64) {
            out[orow + tid] = 0; out[orow + tid + 256] = 0; out[orow + tid + 512] = 0;
            return;
        }
        irow = (((size_t)b * 64 + i) * 64 + j) * 768;
    } else {
        irow = (size_t)blockIdx.x * 768;
    }
    float v0 = in[irow + tid];
    float v1 = in[irow + tid + 256];
    float v2 = in[irow + tid + 512];
    float s = v0 + v1 + v2;
#pragma unroll
    for (int off = 32; off; off >>= 1) s += __shfl_xor(s, off, 64);
    if ((tid & 63) == 0) sbuf[tid >> 6] = s;
    __syncthreads();
    float mean = (sbuf[0] + sbuf[1] + sbuf[2] + sbuf[3]) * (1.f / 768.f);
    __syncthreads();
    float d0 = v0 - mean, d1 = v1 - mean, d2 = v2 - mean;
    float sq = d0 * d0 + d1 * d1 + d2 * d2;
#pragma unroll
    for (int off = 32; off; off >>= 1) sq += __shfl_xor(sq, off, 64);
    if ((tid & 63) == 0) sbuf[tid >> 6] = sq;
    __syncthreads();
    float var = (sbuf[0] + sbuf[1] + sbuf[2] + sbuf[3]) * (1.f / 768.f);
    float rs = rsqrtf(var + 1e-6f);
    out[orow + tid]       = f2b(d0 * rs * g[tid]       + beta[tid]);
    out[orow + tid + 256] = f2b(d1 * rs * g[tid + 256] + beta[tid + 256]);
    out[orow + tid + 512] = f2b(d2 * rs * g[tid + 512] + beta[tid + 512]);
}

// ---------------------------------------------------------------- GEMM
// C(MxN) = A(MxK) @ Bt(NxK)^T + bias, bf16 in / f32 acc, MFMA 16x16x32.
// 128x128 tile, BK=32. Staging via global_load_lds width=16:
// instr t=2*wave+j covers tile rows [16t,16t+16): lane i -> global
// row m0+16t+(i>>2), col k0+(i&3)*8 == LDS base(t*512 elems) + lane*16 B.
// Tail rows >= M stage garbage; consumed only by epilogue rows >= M (skipped).
#define BM 128
#define BN 128
#define BK 32

template <int EPI>
__global__ __launch_bounds__(256) void gemm_bt(
    const u16* __restrict__ A, const u16* __restrict__ Bt,
    const float* __restrict__ bias, void* __restrict__ CoutV,
    const float* __restrict__ resid, int M, int N, int K, int row_base)
{
    __shared__ __align__(16) u16 As[BM * BK];
    __shared__ __align__(16) u16 Bs[BN * BK];
    const int tid = threadIdx.x;
    const int lane = tid & 63, wave = tid >> 6;
    const int wr = wave >> 1, wc = wave & 1;
    const int quad = lane >> 4, l16 = lane & 15;
    const int ntile = N / BN;
    const int m0 = (blockIdx.x / ntile) * BM;
    const int n0 = (blockIdx.x % ntile) * BN;

    f32x4 acc[4][4] = {};

    // per-lane source offsets for the two staging instructions of this wave
    const int t0 = wave * 2;
    const size_t arow0 = (size_t)(m0 + t0 * 16 + (lane >> 2)) * K + (lane & 3) * 8;
    const size_t arow1 = arow0 + (size_t)16 * K;
    const size_t brow0 = (size_t)(n0 + t0 * 16 + (lane >> 2)) * K + (lane & 3) * 8;
    const size_t brow1 = brow0 + (size_t)16 * K;
    u16* lA0 = As + t0 * 16 * BK;
    u16* lA1 = As + (t0 + 1) * 16 * BK;
    u16* lB0 = Bs + t0 * 16 * BK;
    u16* lB1 = Bs + (t0 + 1) * 16 * BK;

    for (int k0 = 0; k0 < K; k0 += BK) {
        __syncthreads();                     // previous tile fully consumed
        gload16(A + arow0 + k0, lA0);
        gload16(A + arow1 + k0, lA1);
        gload16(Bt + brow0 + k0, lB0);
        gload16(Bt + brow1 + k0, lB1);
        __syncthreads();                     // drain vmcnt (compiler-inserted)
        short8 af[4], bfr[4];
#pragma unroll
        for (int i = 0; i < 4; i++)
            af[i] = *(const short8*)(As + (wr * 64 + i * 16 + l16) * BK + quad * 8);
#pragma unroll
        for (int i = 0; i < 4; i++)
            bfr[i] = *(const short8*)(Bs + (wc * 64 + i * 16 + l16) * BK + quad * 8);
#pragma unroll
        for (int mi = 0; mi < 4; mi++)
#pragma unroll
            for (int ni = 0; ni < 4; ni++)
                acc[mi][ni] = __builtin_amdgcn_mfma_f32_16x16x32_bf16(
                    af[mi], bfr[ni], acc[mi][ni], 0, 0, 0);
    }

#pragma unroll
    for (int mi = 0; mi < 4; mi++) {
#pragma unroll
        for (int ni = 0; ni < 4; ni++) {
            const int gn = n0 + wc * 64 + ni * 16 + l16;
            const float bv = bias[gn];
#pragma unroll
            for (int r = 0; r < 4; r++) {
                const int row = m0 + wr * 64 + mi * 16 + quad * 4 + r;
                if (row >= M) continue;
                float v = acc[mi][ni][r] + bv;
                if (EPI == 0) {
                    ((u16*)CoutV)[(size_t)row * N + gn] = f2b(v);
                } else if (EPI == 1) {
                    int grow = row_base + row;
                    int win = grow / 196, t = grow % 196;
                    int p = t / 14, q = t % 14;
                    int b = win / 25, wt = win % 25;
                    int i = (wt / 5) * 14 + p, j = (wt % 5) * 14 + q;
                    if (i < 64 && j < 64) {
                        size_t idx = (((size_t)b * 64 + i) * 64 + j) * 768 + gn;
                        ((float*)CoutV)[idx] = resid[idx] + v;
                    }
                } else if (EPI == 2) {
                    float gl = 0.5f * v * (1.0f + erff(v * 0.70710678118654752f));
                    ((u16*)CoutV)[(size_t)row * N + gn] = f2b(gl);
                } else {
                    size_t idx = (size_t)(row_base + row) * 768 + gn;
                    ((float*)CoutV)[idx] = resid[idx] + v;
                }
            }
        }
    }
}

// ---------------------------------------------------------------- attention v3
// (unchanged from R5 — verified passing)
#define AT_W 72
#define PB_W 40

__global__ __launch_bounds__(256) void attn_mfma(
    const u16* __restrict__ qkv,          // [nw*196][2304] = [..][3][12][64]
    const float* __restrict__ relh, const float* __restrict__ relw, // [27][64]
    u16* __restrict__ out)                // [nw*196][768]
{
    __shared__ __align__(16) u16 rel_ext[256 * 32];      // 16384 B
    __shared__ __align__(16) u16 Kc[64 * AT_W];          //  9216 B
    __shared__ __align__(16) u16 Vt[64 * AT_W];          //  9216 B
    __shared__ __align__(16) u16 pbuf[4][64 * PB_W];     // 20480 B

    const int win = blockIdx.x / 12, head = blockIdx.x % 12;
    const int tid = threadIdx.x, lane = tid & 63, wave = tid >> 6;
    const int quad = lane >> 4, l16 = lane & 15;
    const size_t base = (size_t)win * 196 * 2304 + (size_t)head * 64;

    short8 qf[4][2];
#pragma unroll
    for (int mi = 0; mi < 4; mi++) {
        int tok = wave * 64 + mi * 16 + l16;
        int rt = tok < 196 ? tok : 195;
        const u16* qp = qkv + base + (size_t)rt * 2304 + quad * 8;
        qf[mi][0] = *(const short8*)(qp);
        qf[mi][1] = *(const short8*)(qp + 32);
    }

    for (int e = tid; e < 64 * 64; e += 256) {
        int rr = e >> 6, cc = e & 63;
        float v = 0.f;
        if (rr < 27)      v = 8.f * relh[rr * 64 + cc];
        else if (rr < 54) v = 8.f * relw[(rr - 27) * 64 + cc];
        Kc[rr * AT_W + cc] = f2b(v);
    }
    {
        u16* rp = rel_ext + tid * 32;
        uint4 z = make_uint4(0u, 0u, 0u, 0u);
        *(uint4*)(rp) = z; *(uint4*)(rp + 8) = z;
        *(uint4*)(rp + 16) = z; *(uint4*)(rp + 24) = z;
        rp[31] = f2b(-1e30f);
    }
    __syncthreads();

#pragma unroll
    for (int cb = 0; cb < 2; cb++) {
#pragma unroll
        for (int nt = 0; nt < 2; nt++) {
            const u16* kp_ = Kc + (cb * 32 + nt * 16 + l16) * AT_W + quad * 8;
            short8 b0 = *(const short8*)(kp_);
            short8 b1 = *(const short8*)(kp_ + 32);
            int i = cb * 32 + nt * 16 + l16;
#pragma unroll
            for (int mi = 0; mi < 4; mi++) {
                f32x4 c = {};
                c = __builtin_amdgcn_mfma_f32_16x16x32_bf16(qf[mi][0], b0, c, 0, 0, 0);
                c = __builtin_amdgcn_mfma_f32_16x16x32_bf16(qf[mi][1], b1, c, 0, 0, 0);
#pragma unroll
                for (int r = 0; r < 4; r++) {
                    int row = wave * 64 + mi * 16 + quad * 4 + r;
                    int rowB = row < 196 ? row : 195;
                    int p = rowB / 14, qq = rowB % 14;
                    if (i < 27) {
                        int t = p + 13 - i;
                        if (t >= 0 && t < 14) rel_ext[row * 32 + t] = f2b(c[r]);
                    } else if (i < 54) {
                        int t = qq + 13 - (i - 27);
                        if (t >= 0 && t < 14) rel_ext[row * 32 + 14 + t] = f2b(c[r]);
                    }
                }
            }
        }
    }
    short8 qe[4];
#pragma unroll
    for (int mi = 0; mi < 4; mi++)
        qe[mi] = *(const short8*)(rel_ext + (wave * 64 + mi * 16 + l16) * 32 + quad * 8);

    f32x4 acc[4][4] = {};
    float ml_[4][4], ll_[4][4];
#pragma unroll
    for (int mi = 0; mi < 4; mi++)
#pragma unroll
        for (int r = 0; r < 4; r++) { ml_[mi][r] = -1e30f; ll_[mi][r] = 0.f; }

#pragma unroll 1
    for (int c = 0; c < 4; c++) {
        const int kbase = c * 64;
        __syncthreads();
        {
            int key = tid >> 2;
            int cg  = (tid & 3) << 4;
            int gk = kbase + key;
            uint4 k0 = make_uint4(0u,0u,0u,0u), k1 = k0, v0 = k0, v1 = k0;
            if (gk < 196) {
                const u16* kp_ = qkv + base + 768  + (size_t)gk * 2304 + cg;
                const u16* vp_ = qkv + base + 1536 + (size_t)gk * 2304 + cg;
                k0 = *(const uint4*)(kp_); k1 = *(const uint4*)(kp_ + 8);
                v0 = *(const uint4*)(vp_); v1 = *(const uint4*)(vp_ + 8);
            }
            *(uint4*)(Kc + key * AT_W + cg)     = k0;
            *(uint4*)(Kc + key * AT_W + cg + 8) = k1;
            union { uint4 u; u16 h[8]; } a, b; a.u = v0; b.u = v1;
#pragma unroll
            for (int i = 0; i < 8; i++) Vt[(cg + i) * AT_W + key] = a.h[i];
#pragma unroll
            for (int i = 0; i < 8; i++) Vt[(cg + 8 + i) * AT_W + key] = b.h[i];
        }
        __syncthreads();

        short8 bo[4];
        {
            const u16 one = 0x3F80;
#pragma unroll
            for (int nt = 0; nt < 4; nt++) {
                int key = kbase + nt * 16 + l16;
                int inval = key >= 196;
                int kp = key / 14, kq = key - kp * 14;
                union { short8 s; u16 h[8]; } u;
#pragma unroll
                for (int j = 0; j < 8; j++) {
                    int t = quad * 8 + j;
                    u16 v = 0;
                    if (!inval && t == kp) v = one;
                    if (!inval && t >= 14 && (t - 14) == kq) v = one;
                    if (inval && t == 31) v = one;
                    u.h[j] = v;
                }
                bo[nt] = u.s;
            }
        }

        f32x4 s23[4][2];
#pragma unroll
        for (int mi = 0; mi < 4; mi++) {
            f32x4 s[4];
#pragma unroll
            for (int nt = 0; nt < 4; nt++) {
                const u16* kp_ = Kc + (nt * 16 + l16) * AT_W + quad * 8;
                short8 kf0 = *(const short8*)(kp_);
                short8 kf1 = *(const short8*)(kp_ + 32);
                f32x4 t = {};
                t = __builtin_amdgcn_mfma_f32_16x16x32_bf16(qf[mi][0], kf0, t, 0, 0, 0);
                t = __builtin_amdgcn_mfma_f32_16x16x32_bf16(qf[mi][1], kf1, t, 0, 0, 0);
                t = __builtin_amdgcn_mfma_f32_16x16x32_bf16(qe[mi],    bo[nt], t, 0, 0, 0);
                s[nt] = t * 0.125f;
            }
#pragma unroll
            for (int r = 0; r < 4; r++) {
                float mx = fmaxf(fmaxf(s[0][r], s[1][r]), fmaxf(s[2][r], s[3][r]));
#pragma unroll
                for (int off = 8; off; off >>= 1) mx = fmaxf(mx, __shfl_xor(mx, off, 16));
                float mo = ml_[mi][r];
                float mn = fmaxf(mo, mx);
                float alpha = __expf(mo - mn);
                ml_[mi][r] = mn;
                float p0 = __expf(s[0][r] - mn), p1 = __expf(s[1][r] - mn);
                float p2 = __expf(s[2][r] - mn), p3 = __expf(s[3][r] - mn);
                float ps = (p0 + p1) + (p2 + p3);
#pragma unroll
                for (int off = 8; off; off >>= 1) ps += __shfl_xor(ps, off, 16);
                ll_[mi][r] = ll_[mi][r] * alpha + ps;
#pragma unroll
                for (int ni = 0; ni < 4; ni++) acc[mi][ni][r] *= alpha;
                s[0][r] = p0; s[1][r] = p1; s[2][r] = p2; s[3][r] = p3;
            }
#pragma unroll
            for (int nt = 0; nt < 2; nt++)
#pragma unroll
                for (int r = 0; r < 4; r++)
                    pbuf[wave][(mi * 16 + quad * 4 + r) * PB_W + nt * 16 + l16] = f2b(s[nt][r]);
            s23[mi][0] = s[2]; s23[mi][1] = s[3];
        }

#pragma unroll
        for (int mi = 0; mi < 4; mi++) {
            short8 pf = *(const short8*)(pbuf[wave] + (mi * 16 + l16) * PB_W + quad * 8);
#pragma unroll
            for (int ni = 0; ni < 4; ni++) {
                short8 vfn = *(const short8*)(Vt + (ni * 16 + l16) * AT_W + quad * 8);
                acc[mi][ni] = __builtin_amdgcn_mfma_f32_16x16x32_bf16(pf, vfn, acc[mi][ni], 0, 0, 0);
            }
        }
#pragma unroll
        for (int mi = 0; mi < 4; mi++)
#pragma unroll
            for (int h = 0; h < 2; h++)
#pragma unroll
                for (int r = 0; r < 4; r++)
                    pbuf[wave][(mi * 16 + quad * 4 + r) * PB_W + h * 16 + l16] = f2b(s23[mi][h][r]);
#pragma unroll
        for (int mi = 0; mi < 4; mi++) {
            short8 pf = *(const short8*)(pbuf[wave] + (mi * 16 + l16) * PB_W + quad * 8);
#pragma unroll
            for (int ni = 0; ni < 4; ni++) {
                short8 vfn = *(const short8*)(Vt + (ni * 16 + l16) * AT_W + 32 + quad * 8);
                acc[mi][ni] = __builtin_amdgcn_mfma_f32_16x16x32_bf16(pf, vfn, acc[mi][ni], 0, 0, 0);
            }
        }
    }

#pragma unroll
    for (int mi = 0; mi < 4; mi++)
#pragma unroll
        for (int r = 0; r < 4; r++) {
            int tok = wave * 64 + mi * 16 + quad * 4 + r;
            if (tok < 196) {
                float inv = 1.f / ll_[mi][r];
                size_t ob = (size_t)(win * 196 + tok) * 768 + head * 64;
#pragma unroll
                for (int ni = 0; ni < 4; ni++)
                    out[ob + ni * 16 + l16] = f2b(acc[mi][ni][r] * inv);
            }
        }
}

// ---------------------------------------------------------------- launch
extern "C" void kernel_launch(void* const* d_in, const int* in_sizes, int n_in,
                              void* d_out, int out_size, void* d_ws, size_t ws_size,
                              hipStream_t stream)
{
    const float* x      = (const float*)d_in[0];
    const float* g1     = (const float*)d_in[1];
    const float* beta1  = (const float*)d_in[2];
    const float* w_qkv  = (const float*)d_in[3];
    const float* b_qkv  = (const float*)d_in[4];
    const float* w_proj = (const float*)d_in[5];
    const float* b_proj = (const float*)d_in[6];
    const float* rph    = (const float*)d_in[7];
    const float* rpw    = (const float*)d_in[8];
    const float* g2     = (const float*)d_in[9];
    const float* beta2  = (const float*)d_in[10];
    const float* w_fc1  = (const float*)d_in[11];
    const float* b_fc1  = (const float*)d_in[12];
    const float* w_fc2  = (const float*)d_in[13];
    const float* b_fc2  = (const float*)d_in[14];
    float* out = (float*)d_out;

    const size_t WT = 14155776;
    size_t b1 = 0, b2 = 0;
    int nc = 0, mc = 0;
    auto fits = [&](int a, int m) -> bool {
        size_t rows = (size_t)(200 / a) * 196, toks = (size_t)32768 / m;
        size_t bb1 = rows * 768 * 2 >= toks * 768 * 2 ? rows * 768 * 2 : toks * 768 * 2;
        size_t bb2 = rows * 2304 * 2 >= toks * 3072 * 2 ? rows * 2304 * 2 : toks * 3072 * 2;
        if (WT + bb1 + bb2 <= ws_size) { b1 = bb1; b2 = bb2; nc = a; mc = m; return true; }
        return false;
    };
    if (!fits(1, 1) && !fits(1, 2) && !fits(2, 2) && !fits(2, 4) && !fits(4, 4))
        return;   // diagnostic: leaves d_out untouched

    char* ws = (char*)d_ws;
    u16* wt0 = (u16*)ws;                               // qkv^T  2304x768
    u16* wt1 = wt0 + 2304 * 768;                       // proj^T  768x768
    u16* wt2 = wt1 + 768 * 768;                        // fc1^T  3072x768
    u16* wt3 = wt2 + 3072 * 768;                       // fc2^T   768x3072
    u16* buf1 = (u16*)(ws + WT);
    u16* buf2 = (u16*)(ws + WT + b1);

    dim3 blk(256);

    transpose_k<<<(768/32)*(2304/32), blk, 0, stream>>>(w_qkv,  wt0, 768, 2304);
    transpose_k<<<(768/32)*(768/32),  blk, 0, stream>>>(w_proj, wt1, 768, 768);
    transpose_k<<<(768/32)*(3072/32), blk, 0, stream>>>(w_fc1,  wt2, 768, 3072);
    transpose_k<<<(3072/32)*(768/32), blk, 0, stream>>>(w_fc2,  wt3, 3072, 768);

    // ---- attention phase: nc chunks of (200/nc) windows ----
    {
        const int nw = 200 / nc, rows = nw * 196;
        const int mt = (rows + 127) / 128;
        for (int c = 0; c < nc; c++) {
            const int rb = c * rows;
            ln_kernel<<<rows, blk, 0, stream>>>(x, g1, beta1, buf1, 1, rb);
            gemm_bt<0><<<dim3(mt * (2304/128)), blk, 0, stream>>>(
                buf1, wt0, b_qkv, buf2, nullptr, rows, 2304, 768, 0);
            attn_mfma<<<nw * 12, blk, 0, stream>>>(buf2, rph, rpw, buf1);
            gemm_bt<1><<<dim3(mt * (768/128)), blk, 0, stream>>>(
                buf1, wt1, b_proj, out, x, rows, 768, 768, rb);
        }
    }

    // ---- MLP phase: mc chunks of (32768/mc) tokens ----
    {
        const int tk = 32768 / mc;
        const int mt2 = tk / 128;
        for (int c = 0; c < mc; c++) {
            const int rb = c * tk;
            ln_kernel<<<tk, blk, 0, stream>>>(
                out + (size_t)rb * 768, g2, beta2, buf1, 0, 0);
            gemm_bt<2><<<dim3(mt2 * (3072/128)), blk, 0, stream>>>(
                buf1, wt2, b_fc1, buf2, nullptr, tk, 3072, 768, 0);
            gemm_bt<3><<<dim3(mt2 * (768/128)), blk, 0, stream>>>(
                buf2, wt3, b_fc2, out, out, tk, 768, 3072, rb);
        }
    }
}